// Round 1
// baseline (454.866 us; speedup 1.0000x reference)
//
#include <hip/hip_runtime.h>
#include <hip/hip_bf16.h>

// Problem constants
#define KTOT   268203          // 3*299*299
#define MROWS  256             // B*T = 4*64
#define NCOLS  512             // D1
#define HDIM   28
#define NSTEPS_TOTAL ((KTOT + 31) / 32)   // 8382 K-steps of 32

typedef __attribute__((ext_vector_type(4))) float  f32x4;
typedef __attribute__((ext_vector_type(4))) __bf16 bf16x4;
typedef __attribute__((ext_vector_type(8))) __bf16 bf16x8;

// -------------------------------------------------------------------------
// Kernel 1: split-K GEMM  part[ks] += x[256 x Kchunk] * W1[Kchunk x 128cols]
// BM=256 (full M), BN=128, BK=32. 512 threads = 8 waves (4x2 of 64x64 tiles).
// fp32 global loads (scalar dword: x rows start at odd-float offsets),
// convert to bf16, stage in padded LDS, mfma_f32_16x16x32_bf16.
// -------------------------------------------------------------------------
__global__ __launch_bounds__(512) void gemm1_kernel(
    const float* __restrict__ x, const float* __restrict__ W1,
    float* __restrict__ part, int steps_per)
{
    __shared__ __hip_bfloat16 Alds[MROWS][40];   // rows padded 32->40 (bank-conflict-free b128 reads)
    __shared__ __hip_bfloat16 Blds[128][40];     // stored transposed: [col][k]

    const int tid  = threadIdx.x;
    const int lane = tid & 63;
    const int w    = tid >> 6;
    const int wm   = w >> 1;                 // 0..3 : wave row (64 rows each)
    const int wn   = w & 1;                  // 0..1 : wave col (64 cols each)
    const int bcol = blockIdx.x * 128;       // N-tile base (0,128,256,384)
    const int ks   = blockIdx.y;             // split-K index

    // A staging map: thread covers rows (tid>>5)+16i, k = tid&31  (coalesced 128B/row)
    const int arow0 = tid >> 5;              // 0..15
    const int ak    = tid & 31;              // 0..31
    // B staging map: thread gathers 4 k's (stride-512 rows) for one col (coalesced per k-row)
    const int bc    = tid & 127;             // 0..127
    const int bkg   = tid >> 7;              // 0..3  (+4 on second pass -> kg 0..7)

    f32x4 acc[4][4];
    #pragma unroll
    for (int i = 0; i < 4; ++i)
        #pragma unroll
        for (int j = 0; j < 4; ++j)
            acc[i][j] = (f32x4){0.f, 0.f, 0.f, 0.f};

    int s0 = ks * steps_per;
    int s1 = s0 + steps_per;
    if (s1 > NSTEPS_TOTAL) s1 = NSTEPS_TOTAL;

    for (int s = s0; s < s1; ++s) {
        const long kb = (long)s * 32;
        float areg[16];
        float breg[2][4];
        const bool full = (kb + 32 <= KTOT);
        if (full) {
            const float* xa = x + (size_t)arow0 * KTOT + kb + ak;
            #pragma unroll
            for (int i = 0; i < 16; ++i)
                areg[i] = xa[(size_t)i * 16 * KTOT];
            #pragma unroll
            for (int g = 0; g < 2; ++g) {
                const int kg = bkg + g * 4;
                #pragma unroll
                for (int j = 0; j < 4; ++j)
                    breg[g][j] = W1[(size_t)(kb + kg * 4 + j) * NCOLS + bcol + bc];
            }
        } else {
            // only the globally-last K-step (K%32 == 11) takes this path
            const long k = kb + ak;
            #pragma unroll
            for (int i = 0; i < 16; ++i)
                areg[i] = (k < KTOT) ? x[(size_t)(arow0 + i * 16) * KTOT + k] : 0.f;
            #pragma unroll
            for (int g = 0; g < 2; ++g) {
                const int kg = bkg + g * 4;
                #pragma unroll
                for (int j = 0; j < 4; ++j) {
                    const long kk = kb + kg * 4 + j;
                    breg[g][j] = (kk < KTOT) ? W1[(size_t)kk * NCOLS + bcol + bc] : 0.f;
                }
            }
        }

        __syncthreads();   // previous iteration's LDS reads done

        #pragma unroll
        for (int i = 0; i < 16; ++i)
            Alds[arow0 + i * 16][ak] = __float2bfloat16(areg[i]);
        #pragma unroll
        for (int g = 0; g < 2; ++g) {
            union { bf16x4 v; __hip_bfloat16 h[4]; } p;
            #pragma unroll
            for (int j = 0; j < 4; ++j) p.h[j] = __float2bfloat16(breg[g][j]);
            *(bf16x4*)&Blds[bc][(bkg + g * 4) * 4] = p.v;
        }

        __syncthreads();

        // fragments: row/col = lane&15, per-lane k block = (lane>>4)*8 (A and B use the
        // SAME ordering, so any per-lane k permutation cancels in the dot product)
        const int krd = (lane >> 4) * 8;
        const int rc  = lane & 15;
        bf16x8 af[4], bq[4];
        #pragma unroll
        for (int mi = 0; mi < 4; ++mi)
            af[mi] = *(const bf16x8*)&Alds[wm * 64 + mi * 16 + rc][krd];
        #pragma unroll
        for (int ni = 0; ni < 4; ++ni)
            bq[ni] = *(const bf16x8*)&Blds[wn * 64 + ni * 16 + rc][krd];
        #pragma unroll
        for (int mi = 0; mi < 4; ++mi)
            #pragma unroll
            for (int ni = 0; ni < 4; ++ni)
                acc[mi][ni] = __builtin_amdgcn_mfma_f32_16x16x32_bf16(
                    af[mi], bq[ni], acc[mi][ni], 0, 0, 0);
    }

    // store partials; C/D layout: col = lane&15, row = (lane>>4)*4 + reg  [guide-verified]
    float* outp = part + (size_t)ks * MROWS * NCOLS;
    #pragma unroll
    for (int mi = 0; mi < 4; ++mi) {
        const int r0 = wm * 64 + mi * 16 + ((lane >> 4) * 4);
        #pragma unroll
        for (int ni = 0; ni < 4; ++ni) {
            const int c = bcol + wn * 64 + ni * 16 + (lane & 15);
            #pragma unroll
            for (int j = 0; j < 4; ++j)
                outp[(size_t)(r0 + j) * NCOLS + c] = acc[mi][ni][j];
        }
    }
}

// -------------------------------------------------------------------------
// Kernel 2: reduce split-K partials + b1 + relu -> h1 row (LDS) -> u = h1@Wi
// one block per (b,t) row
// -------------------------------------------------------------------------
__global__ __launch_bounds__(256) void reduce_u_kernel(
    const float* __restrict__ part, const float* __restrict__ b1,
    const float* __restrict__ Wi, float* __restrict__ u, int nks)
{
    __shared__ float h1[NCOLS];
    const int row = blockIdx.x;
    const int tid = threadIdx.x;
    #pragma unroll
    for (int cc = 0; cc < 2; ++cc) {
        const int c = tid + cc * 256;
        float sum = 0.f;
        for (int k = 0; k < nks; ++k)
            sum += part[((size_t)k * MROWS + row) * NCOLS + c];
        sum += b1[c];
        h1[c] = fmaxf(sum, 0.f);
    }
    __syncthreads();
    if (tid < HDIM) {
        float sum = 0.f;
        for (int d = 0; d < NCOLS; ++d)
            sum += h1[d] * Wi[d * HDIM + tid];
        u[row * HDIM + tid] = sum;
    }
}

// -------------------------------------------------------------------------
// Kernel 3: LTC recurrence (T=64, fp32, exact reference semantics) + head
// 1 block, 128 threads: batch = tid>>5 (4), unit j = tid&31 (28 active)
// -------------------------------------------------------------------------
__global__ __launch_bounds__(128) void recur_kernel(
    const float* __restrict__ u, const float* __restrict__ Wr,
    const float* __restrict__ br, const float* __restrict__ Av,
    const float* __restrict__ tau, const float* __restrict__ W2,
    const float* __restrict__ b2, float* __restrict__ out)
{
    __shared__ float h[4][HDIM];
    __shared__ float wrs[HDIM * HDIM];
    __shared__ float brs[HDIM], As[HDIM], its[HDIM];
    const int tid = threadIdx.x;
    const int b = tid >> 5;
    const int j = tid & 31;
    for (int i = tid; i < HDIM * HDIM; i += 128) wrs[i] = Wr[i];
    if (tid < HDIM) { brs[tid] = br[tid]; As[tid] = Av[tid]; its[tid] = 1.f / tau[tid]; }
    if (j < HDIM) h[b][j] = 0.f;
    __syncthreads();
    for (int t = 0; t < 64; ++t) {
        float hn = 0.f;
        if (j < HDIM) {
            float a = u[(b * 64 + t) * HDIM + j] + brs[j];
            #pragma unroll
            for (int i = 0; i < HDIM; ++i) a += h[b][i] * wrs[i * HDIM + j];
            const float ft = 1.f / (1.f + expf(-a));
            hn = (h[b][j] + ft * As[j]) / (1.f + its[j] + ft);
        }
        __syncthreads();
        if (j < HDIM) h[b][j] = hn;
        __syncthreads();
    }
    if (tid < 8) {
        const int bb = tid >> 1, o = tid & 1;
        float sacc = b2[o];
        #pragma unroll
        for (int i = 0; i < HDIM; ++i) sacc += fmaxf(h[bb][i], 0.f) * W2[i * 2 + o];
        out[bb * 2 + o] = 1.f / (1.f + expf(-sacc));
    }
}

// -------------------------------------------------------------------------
extern "C" void kernel_launch(void* const* d_in, const int* in_sizes, int n_in,
                              void* d_out, int out_size, void* d_ws, size_t ws_size,
                              hipStream_t stream)
{
    (void)in_sizes; (void)n_in; (void)out_size;
    const float* x   = (const float*)d_in[0];
    const float* W1  = (const float*)d_in[1];
    const float* b1  = (const float*)d_in[2];
    const float* Wi  = (const float*)d_in[3];
    const float* Wr  = (const float*)d_in[4];
    const float* br  = (const float*)d_in[5];
    const float* Av  = (const float*)d_in[6];
    const float* tau = (const float*)d_in[7];
    const float* W2  = (const float*)d_in[8];
    const float* b2  = (const float*)d_in[9];
    float* out = (float*)d_out;

    // split-K sized from workspace (deterministic: ws_size is fixed per harness)
    const size_t per_split = (size_t)MROWS * NCOLS * sizeof(float);   // 512 KiB
    long ksl = ((long)ws_size - 65536) / (long)per_split;
    int ksplit = (int)(ksl > 128 ? 128 : (ksl < 1 ? 1 : ksl));
    const int steps_per = (NSTEPS_TOTAL + ksplit - 1) / ksplit;
    const int nks = (NSTEPS_TOTAL + steps_per - 1) / steps_per;

    float* part = (float*)d_ws;
    float* u    = part + (size_t)nks * MROWS * NCOLS;

    gemm1_kernel<<<dim3(4, nks), 512, 0, stream>>>(x, W1, part, steps_per);
    reduce_u_kernel<<<dim3(MROWS), 256, 0, stream>>>(part, b1, Wi, u, nks);
    recur_kernel<<<dim3(1), 128, 0, stream>>>(u, Wr, br, Av, tau, W2, b2, out);
}

// Round 2
// 342.573 us; speedup vs baseline: 1.3278x; 1.3278x over previous
//
#include <hip/hip_runtime.h>
#include <hip/hip_bf16.h>

// Problem constants
#define KTOT   268203          // 3*299*299
#define MROWS  256             // B*T = 4*64
#define NCOLS  512             // D1
#define HDIM   28
#define NSTEPS_TOTAL ((KTOT + 31) / 32)   // 8382 K-steps of 32

typedef __attribute__((ext_vector_type(4))) float  f32x4;
typedef __attribute__((ext_vector_type(4))) __bf16 bf16x4;
typedef __attribute__((ext_vector_type(8))) __bf16 bf16x8;

// -------------------------------------------------------------------------
// Kernel 1: split-K GEMM  part[ks] = x[256 x Kchunk] * W1[Kchunk x 128cols]
// BM=256 (full M), BN=128, BK=32. 512 threads = 8 waves (4x2 of 64x64 tiles).
// Register-prefetch 2-phase pipeline: while MFMA'ing step s, step s+1's
// global loads are already in flight (issued before the barrier).
// XCD swizzle: the 4 N-tile blocks sharing one x-chunk get block ids that are
// congruent mod 8 -> same XCD -> x-chunk served from that XCD's L2 once.
// -------------------------------------------------------------------------
__global__ __launch_bounds__(512) void gemm1_kernel(
    const float* __restrict__ x, const float* __restrict__ W1,
    float* __restrict__ part, int steps_per, int nks)
{
    __shared__ __hip_bfloat16 Alds[MROWS][40];   // rows padded 32->40 (2-way max on b128 reads)
    __shared__ __hip_bfloat16 Blds[128][40];     // stored transposed: [col][k]

    const int tid  = threadIdx.x;
    const int lane = tid & 63;
    const int w    = tid >> 6;
    const int wm   = w >> 1;                 // 0..3 : wave row (64 rows each)
    const int wn   = w & 1;                  // 0..1 : wave col (64 cols each)

    // block-id swizzle: id = (ks&7) + 8*(bx + 4*(ks>>3))  -> invert
    int bx, ks;
    {
        const int id = blockIdx.x;
        if ((nks & 7) == 0) {
            const int xcd  = id & 7;
            const int rest = id >> 3;
            bx = rest & 3;
            ks = ((rest >> 2) << 3) | xcd;
        } else {                              // fallback: plain mapping
            bx = id & 3;
            ks = id >> 2;
        }
    }
    const int bcol = bx * 128;

    // A staging map: thread covers rows (tid>>5)+16i, k = tid&31  (coalesced 128B/row)
    const int arow0 = tid >> 5;              // 0..15
    const int ak    = tid & 31;              // 0..31
    // B staging map: thread gathers 8 k's (two groups of 4) for one col
    const int bc    = tid & 127;             // 0..127
    const int bkg   = tid >> 7;              // 0..3

    f32x4 acc[4][4];
    #pragma unroll
    for (int i = 0; i < 4; ++i)
        #pragma unroll
        for (int j = 0; j < 4; ++j)
            acc[i][j] = (f32x4){0.f, 0.f, 0.f, 0.f};

    const int s0 = ks * steps_per;
    int s1 = s0 + steps_per;
    if (s1 > NSTEPS_TOTAL) s1 = NSTEPS_TOTAL;

    auto load_tile = [&](int s, float* areg, float* breg) {
        const long kb = (long)s * 32;
        if (kb + 32 <= KTOT) {
            const float* xa = x + (size_t)arow0 * KTOT + kb + ak;
            #pragma unroll
            for (int i = 0; i < 16; ++i)
                areg[i] = xa[(size_t)i * 16 * KTOT];
            #pragma unroll
            for (int g = 0; g < 2; ++g) {
                const int kg = bkg + g * 4;
                #pragma unroll
                for (int j = 0; j < 4; ++j)
                    breg[g * 4 + j] = W1[(size_t)(kb + kg * 4 + j) * NCOLS + bcol + bc];
            }
        } else {
            // only the globally-last K-step (K%32 == 11) takes this path
            const long k = kb + ak;
            #pragma unroll
            for (int i = 0; i < 16; ++i)
                areg[i] = (k < KTOT) ? x[(size_t)(arow0 + i * 16) * KTOT + k] : 0.f;
            #pragma unroll
            for (int g = 0; g < 2; ++g) {
                const int kg = bkg + g * 4;
                #pragma unroll
                for (int j = 0; j < 4; ++j) {
                    const long kk = kb + kg * 4 + j;
                    breg[g * 4 + j] = (kk < KTOT) ? W1[(size_t)kk * NCOLS + bcol + bc] : 0.f;
                }
            }
        }
    };

    auto store_tile = [&](const float* areg, const float* breg) {
        #pragma unroll
        for (int i = 0; i < 16; ++i)
            Alds[arow0 + i * 16][ak] = __float2bfloat16(areg[i]);
        #pragma unroll
        for (int g = 0; g < 2; ++g) {
            union { bf16x4 v; __hip_bfloat16 h[4]; } p;
            #pragma unroll
            for (int j = 0; j < 4; ++j) p.h[j] = __float2bfloat16(breg[g * 4 + j]);
            *(bf16x4*)&Blds[bc][(bkg + g * 4) * 4] = p.v;
        }
    };

    auto do_mfma = [&]() {
        // fragments: row/col = lane&15, per-lane k block = (lane>>4)*8 (A and B use the
        // SAME ordering, so any per-lane k permutation cancels in the dot product)
        const int krd = (lane >> 4) * 8;
        const int rc  = lane & 15;
        bf16x8 af[4], bq[4];
        #pragma unroll
        for (int mi = 0; mi < 4; ++mi)
            af[mi] = *(const bf16x8*)&Alds[wm * 64 + mi * 16 + rc][krd];
        #pragma unroll
        for (int ni = 0; ni < 4; ++ni)
            bq[ni] = *(const bf16x8*)&Blds[wn * 64 + ni * 16 + rc][krd];
        #pragma unroll
        for (int mi = 0; mi < 4; ++mi)
            #pragma unroll
            for (int ni = 0; ni < 4; ++ni)
                acc[mi][ni] = __builtin_amdgcn_mfma_f32_16x16x32_bf16(
                    af[mi], bq[ni], acc[mi][ni], 0, 0, 0);
    };

    if (s0 < s1) {
        float aA[16], bA[8], aB[16], bB[8];
        load_tile(s0, aA, bA);
        int s = s0;
        for (;;) {
            __syncthreads();                       // prev iter's LDS reads done
            store_tile(aA, bA);                    // waits vmcnt for loads issued last iter
            if (s + 1 < s1) load_tile(s + 1, aB, bB);  // prefetch next (hides under MFMA)
            __syncthreads();
            do_mfma();
            if (++s >= s1) break;

            __syncthreads();
            store_tile(aB, bB);
            if (s + 1 < s1) load_tile(s + 1, aA, bA);
            __syncthreads();
            do_mfma();
            if (++s >= s1) break;
        }
    }

    // store partials; C/D layout: col = lane&15, row = (lane>>4)*4 + reg  [guide-verified]
    float* outp = part + (size_t)ks * MROWS * NCOLS;
    #pragma unroll
    for (int mi = 0; mi < 4; ++mi) {
        const int r0 = wm * 64 + mi * 16 + ((lane >> 4) * 4);
        #pragma unroll
        for (int ni = 0; ni < 4; ++ni) {
            const int c = bcol + wn * 64 + ni * 16 + (lane & 15);
            #pragma unroll
            for (int j = 0; j < 4; ++j)
                outp[(size_t)(r0 + j) * NCOLS + c] = acc[mi][ni][j];
        }
    }
}

// -------------------------------------------------------------------------
// Kernel 2: reduce split-K partials + b1 + relu -> h1 (LDS) -> u = h1@Wi
// one block per (b,t) row; 512 threads: (k-slice 0..3) x (col-quad 0..127)
// float4 loads, 32 independent loads in flight per thread
// -------------------------------------------------------------------------
__global__ __launch_bounds__(512) void reduce_u_kernel(
    const float* __restrict__ part, const float* __restrict__ b1,
    const float* __restrict__ Wi, float* __restrict__ u, int nks)
{
    __shared__ float h1[NCOLS];
    __shared__ f32x4 red[4][128];
    const int row = blockIdx.x;
    const int tid = threadIdx.x;
    const int c4  = tid & 127;               // column quad
    const int kk  = tid >> 7;                // k-slice 0..3

    f32x4 sum = (f32x4){0.f, 0.f, 0.f, 0.f};
    for (int k = kk; k < nks; k += 4)
        sum += *(const f32x4*)&part[((size_t)k * MROWS + row) * NCOLS + c4 * 4];
    red[kk][c4] = sum;
    __syncthreads();

    if (tid < 128) {
        f32x4 t = red[0][tid] + red[1][tid] + red[2][tid] + red[3][tid];
        const f32x4 bb = *(const f32x4*)&b1[tid * 4];
        t += bb;
        #pragma unroll
        for (int j = 0; j < 4; ++j) h1[tid * 4 + j] = fmaxf(t[j], 0.f);
    }
    __syncthreads();

    // u[row,h] = dot(h1, Wi[:,h]); wave w handles h = 4w..4w+3
    const int wv = tid >> 6, lane = tid & 63;
    #pragma unroll
    for (int hh = 0; hh < 4; ++hh) {
        const int h = wv * 4 + hh;
        if (h < HDIM) {                      // wave-uniform branch
            float p = 0.f;
            #pragma unroll
            for (int dd = 0; dd < 8; ++dd) {
                const int d = lane + dd * 64;
                p += h1[d] * Wi[d * HDIM + h];
            }
            #pragma unroll
            for (int off = 32; off; off >>= 1) p += __shfl_down(p, off);
            if (lane == 0) u[row * HDIM + h] = p;
        }
    }
}

// -------------------------------------------------------------------------
// Kernel 3: LTC recurrence (T=64, fp32, exact reference semantics) + head
// 4 blocks (one per batch) x 1 wave; h lives in lanes, h.Wr via __shfl
// broadcast; all 64 u values prefetched to registers; t-loop fully unrolled
// (static uv[] indexing -> no scratch).
// -------------------------------------------------------------------------
__global__ __launch_bounds__(64) void recur_kernel(
    const float* __restrict__ u, const float* __restrict__ Wr,
    const float* __restrict__ br, const float* __restrict__ Av,
    const float* __restrict__ tau, const float* __restrict__ W2,
    const float* __restrict__ b2, float* __restrict__ out)
{
    const int b = blockIdx.x;
    const int j = threadIdx.x;               // 0..63, active j<28
    const bool act = j < HDIM;
    const int jj = act ? j : 0;

    float wr[HDIM];
    #pragma unroll
    for (int i = 0; i < HDIM; ++i) wr[i] = act ? Wr[i * HDIM + jj] : 0.f;
    const float brj = act ? br[jj] : 0.f;
    const float Aj  = act ? Av[jj] : 0.f;
    const float itj = act ? (1.f / tau[jj]) : 0.f;

    float uv[64];
    #pragma unroll
    for (int t = 0; t < 64; ++t)
        uv[t] = act ? u[(b * 64 + t) * HDIM + jj] : 0.f;

    float h = 0.f;
    #pragma unroll
    for (int t = 0; t < 64; ++t) {
        float a = uv[t] + brj;
        #pragma unroll
        for (int i = 0; i < HDIM; ++i)
            a += __shfl(h, i) * wr[i];
        const float ft = 1.f / (1.f + expf(-a));
        const float hn = (h + ft * Aj) / (1.f + itj + ft);
        h = act ? hn : 0.f;
    }

    const float r  = act ? fmaxf(h, 0.f) : 0.f;
    float p0 = act ? r * W2[jj * 2 + 0] : 0.f;
    float p1 = act ? r * W2[jj * 2 + 1] : 0.f;
    #pragma unroll
    for (int off = 32; off; off >>= 1) {
        p0 += __shfl_down(p0, off);
        p1 += __shfl_down(p1, off);
    }
    if (j == 0) {
        out[b * 2 + 0] = 1.f / (1.f + expf(-(p0 + b2[0])));
        out[b * 2 + 1] = 1.f / (1.f + expf(-(p1 + b2[1])));
    }
}

// -------------------------------------------------------------------------
extern "C" void kernel_launch(void* const* d_in, const int* in_sizes, int n_in,
                              void* d_out, int out_size, void* d_ws, size_t ws_size,
                              hipStream_t stream)
{
    (void)in_sizes; (void)n_in; (void)out_size;
    const float* x   = (const float*)d_in[0];
    const float* W1  = (const float*)d_in[1];
    const float* b1  = (const float*)d_in[2];
    const float* Wi  = (const float*)d_in[3];
    const float* Wr  = (const float*)d_in[4];
    const float* br  = (const float*)d_in[5];
    const float* Av  = (const float*)d_in[6];
    const float* tau = (const float*)d_in[7];
    const float* W2  = (const float*)d_in[8];
    const float* b2  = (const float*)d_in[9];
    float* out = (float*)d_out;

    // split-K: prefer 128 (multiple of 8 for XCD swizzle), sized from workspace
    const size_t per_split = (size_t)MROWS * NCOLS * sizeof(float);   // 512 KiB
    long kmax = ((long)ws_size - (1L << 20)) / (long)per_split;
    int nks = 128;
    if (kmax < 128) {
        nks = (int)(kmax & ~7L);             // multiple of 8
        if (nks < 8) nks = (kmax < 1) ? 1 : (int)kmax;
    }
    const int steps_per = (NSTEPS_TOTAL + nks - 1) / nks;

    float* part = (float*)d_ws;
    float* u    = part + (size_t)nks * MROWS * NCOLS;

    gemm1_kernel<<<dim3(4 * nks), 512, 0, stream>>>(x, W1, part, steps_per, nks);
    reduce_u_kernel<<<dim3(MROWS), 512, 0, stream>>>(part, b1, Wi, u, nks);
    recur_kernel<<<dim3(4), 64, 0, stream>>>(u, Wr, br, Av, tau, W2, b2, out);
}